// Round 4
// baseline (4144.392 us; speedup 1.0000x reference)
//
#include <hip/hip_runtime.h>
#include <math.h>

// Problem constants
#define BB 64
#define TT 512
#define II 512
#define HH 1024
#define OO 128
#define GN (3*HH)       // 3072
#define TC 64           // time chunk
#define NCH (TT/TC)     // 8 chunks

using u16 = unsigned short;
typedef __attribute__((ext_vector_type(8))) short bf16x8;
typedef __attribute__((ext_vector_type(4))) float f32x4;
typedef __attribute__((ext_vector_type(4))) unsigned short u16x4;
typedef __attribute__((ext_vector_type(2))) unsigned long long u64x2;

__device__ __forceinline__ u16 f2bf(float f){
  unsigned u = __builtin_bit_cast(unsigned, f);
  u += 0x7fffu + ((u >> 16) & 1u);          // RNE
  return (u16)(u >> 16);
}
__device__ __forceinline__ float bf2f(u16 h){
  unsigned u = ((unsigned)h) << 16;
  return __builtin_bit_cast(float, u);
}

// ---------------------------------------------------------------- f32 -> bf16
__global__ __launch_bounds__(256) void cvt_kernel(const float* __restrict__ s,
                                                  u16* __restrict__ d, int n4){
  int stride = gridDim.x * 256;
  for (int i = blockIdx.x * 256 + threadIdx.x; i < n4; i += stride){
    float4 v = reinterpret_cast<const float4*>(s)[i];
    u16x4 o; o.x = f2bf(v.x); o.y = f2bf(v.y); o.z = f2bf(v.z); o.w = f2bf(v.w);
    reinterpret_cast<u16x4*>(d)[i] = o;
  }
}

// --------------------------------------------- x chunk gather+convert to bf16
__global__ __launch_bounds__(256) void cvtx_chunk(const float* __restrict__ x,
                                                  u16* __restrict__ d, int t0){
  const int per_b = TC * II / 4;
  int stride = gridDim.x * 256;
  for (int i = blockIdx.x * 256 + threadIdx.x; i < BB * per_b; i += stride){
    int b = i / per_b, r = i - b * per_b;
    float4 v = reinterpret_cast<const float4*>(x)[(size_t)(b * TT + t0) * (II/4) + r];
    u16x4 o; o.x = f2bf(v.x); o.y = f2bf(v.y); o.z = f2bf(v.z); o.w = f2bf(v.w);
    reinterpret_cast<u16x4*>(d)[(size_t)b * per_b + r] = o;
  }
}

// ------------------------------------------------- bf16 GEMM: C = A@Bw^T + bias
// m97 structure: 128x128 tile, BK=32, 4 waves, global_load_lds width 16.
template<int K>
__global__ __launch_bounds__(256) void gemm_bias(const u16* __restrict__ A,
    const u16* __restrict__ Bw, const float* __restrict__ bias, u16* __restrict__ C){
  __shared__ u16 As[128*32];
  __shared__ u16 Bs[128*32];
  int tid = threadIdx.x;
  int lane = tid & 63, wave = tid >> 6;
  int m0 = blockIdx.x * 128, n0 = blockIdx.y * 128;
  int wr = (wave >> 1) * 64, wc = (wave & 1) * 64;
  int fr = lane & 15, fo = (lane >> 4) * 8;
  f32x4 acc[4][4] = {};
  for (int k0 = 0; k0 < K; k0 += 32){
    __syncthreads();
    #pragma unroll
    for (int c = 0; c < 2; ++c){
      int chunk = wave * 2 + c;
      int s = chunk * 64 + lane;
      int row = s >> 2, o = s & 3;
      const u16* ga = A  + (size_t)(m0 + row) * K + k0 + o * 8;
      const u16* gb = Bw + (size_t)(n0 + row) * K + k0 + o * 8;
      __builtin_amdgcn_global_load_lds(
          (const __attribute__((address_space(1))) unsigned int*)ga,
          (__attribute__((address_space(3))) unsigned int*)(As + chunk * 512), 16, 0, 0);
      __builtin_amdgcn_global_load_lds(
          (const __attribute__((address_space(1))) unsigned int*)gb,
          (__attribute__((address_space(3))) unsigned int*)(Bs + chunk * 512), 16, 0, 0);
    }
    __syncthreads();
    bf16x8 af[4], bf[4];
    #pragma unroll
    for (int m = 0; m < 4; ++m)
      af[m] = *reinterpret_cast<const bf16x8*>(&As[(wr + m*16 + fr) * 32 + fo]);
    #pragma unroll
    for (int n = 0; n < 4; ++n)
      bf[n] = *reinterpret_cast<const bf16x8*>(&Bs[(wc + n*16 + fr) * 32 + fo]);
    #pragma unroll
    for (int m = 0; m < 4; ++m)
      #pragma unroll
      for (int n = 0; n < 4; ++n)
        acc[m][n] = __builtin_amdgcn_mfma_f32_16x16x32_bf16(af[m], bf[n], acc[m][n], 0, 0, 0);
  }
  int r4 = (lane >> 4) * 4;
  #pragma unroll
  for (int n = 0; n < 4; ++n){
    int col = n0 + wc + n*16 + fr;
    float bv = bias[col];
    #pragma unroll
    for (int m = 0; m < 4; ++m){
      #pragma unroll
      for (int q = 0; q < 4; ++q){
        int row = m0 + wr + m*16 + r4 + q;
        C[(size_t)row * GN + col] = f2bf(acc[m][n][q] + bv);
      }
    }
  }
}

// ------------------------------------------------------------- persistent GRU chunk
// grid = 256 WGs (1/CU via 111.5KB LDS => co-resident). 4 batch-groups x 16 rows;
// 64 WGs/group x 16 cols. W_hh slice resident in LDS. h exchanged via LLC using
// RELAXED agent atomics only (acq/rel would emit buffer_inv/wbl2 L2 scans, ~21us/step
// [R2->R3: 24.6->3.56us/step]).
// R4: per-WAVE signaling. Producer wave owns 4 rows x 16 cols of h: stores h,
// drains ITS stores (s_waitcnt vmcnt(0)), lane0 stores a monotonic step tag.
// No WG barrier on the signal path. Consumer: 64 tags = 1 load/lane + 1 ballot,
// no s_sleep. Parity double-buffer bounds producer lead to 1 step, so
// tag-observe -> h-load is race-free (h was LLC-acked before tag was issued).
__global__ __launch_bounds__(256, 1) void gru_layer(
    const u16* __restrict__ gx, const u16* __restrict__ Whh, const float* __restrict__ bhh,
    u16* hbuf, unsigned* tags, u16* h1c, float* hstate, int base){
  __shared__ u16 Ws[48 * 1032];
  __shared__ float part[4 * 3 * 64 * 4];
  __shared__ float bsh[48];
  int tid = threadIdx.x, lane = tid & 63, w = tid >> 6;
  int g = blockIdx.x & 3, wg = blockIdx.x >> 2;
  int c0 = wg * 16, rb0 = g * 16;
  for (int ch = tid; ch < 48 * 128; ch += 256){
    int r = ch >> 7, o = ch & 127;
    const u16* src = Whh + (size_t)((r >> 4) * HH + c0 + (r & 15)) * HH + o * 8;
    *reinterpret_cast<int4*>(&Ws[r * 1032 + o * 8]) = *reinterpret_cast<const int4*>(src);
  }
  if (tid < 48) bsh[tid] = bhh[(tid >> 4) * HH + c0 + (tid & 15)];
  __syncthreads();
  int b = tid >> 4, j = tid & 15;
  int fr = lane & 15, klo = (lane >> 4) * 8;
  int kw = w * 256;
  const u16* gxp = gx + (size_t)(rb0 + b) * TC * GN + c0 + j;
  // tag array: per group, 64 col-blocks x 4 row-blocks, 64B-padded entries
  unsigned* tgrp  = tags + g * (64 * 4 * 16);
  unsigned* mytag = tgrp + (wg * 4 + w) * 16;                          // producer (lane0)
  unsigned* ptag  = tgrp + ((w * 16 + (lane >> 2)) * 4 + (lane & 3)) * 16;  // consumer poll
  float h_old = hstate[(size_t)(rb0 + b) * HH + c0 + j];
  int par = 0;
  for (int tl = 0; tl < TC; ++tl){
    // gx loads are h-independent — issue before the wait, overlap the poll
    float gxr = bf2f(gxp[(size_t)tl * GN]);
    float gxz = bf2f(gxp[(size_t)tl * GN + HH]);
    float gxn = bf2f(gxp[(size_t)tl * GN + 2 * HH]);
    unsigned want = (unsigned)(base + tl);
    for (;;){
      unsigned v = __hip_atomic_load(ptag, __ATOMIC_RELAXED, __HIP_MEMORY_SCOPE_AGENT);
      if (__all((int)(v >= want))) break;
    }
    asm volatile("" ::: "memory");   // keep h loads below the poll (compiler fence)
    const u16* hrow = hbuf + (size_t)par * (BB*HH) + (size_t)(rb0 + fr) * HH + kw + klo;
    unsigned long long alo[8], ahi[8];
    #pragma unroll
    for (int ks = 0; ks < 8; ++ks){
      alo[ks] = __hip_atomic_load((const unsigned long long*)(hrow + ks * 32),
                                  __ATOMIC_RELAXED, __HIP_MEMORY_SCOPE_AGENT);
      ahi[ks] = __hip_atomic_load((const unsigned long long*)(hrow + ks * 32 + 4),
                                  __ATOMIC_RELAXED, __HIP_MEMORY_SCOPE_AGENT);
    }
    f32x4 acc0 = {}, acc1 = {}, acc2 = {};
    #pragma unroll
    for (int ks = 0; ks < 8; ++ks){
      u64x2 t2; t2.x = alo[ks]; t2.y = ahi[ks];
      bf16x8 af = __builtin_bit_cast(bf16x8, t2);
      int kk = kw + ks * 32 + klo;
      bf16x8 b0 = *reinterpret_cast<const bf16x8*>(&Ws[(      fr) * 1032 + kk]);
      bf16x8 b1 = *reinterpret_cast<const bf16x8*>(&Ws[(16 + fr) * 1032 + kk]);
      bf16x8 b2 = *reinterpret_cast<const bf16x8*>(&Ws[(32 + fr) * 1032 + kk]);
      acc0 = __builtin_amdgcn_mfma_f32_16x16x32_bf16(af, b0, acc0, 0, 0, 0);
      acc1 = __builtin_amdgcn_mfma_f32_16x16x32_bf16(af, b1, acc1, 0, 0, 0);
      acc2 = __builtin_amdgcn_mfma_f32_16x16x32_bf16(af, b2, acc2, 0, 0, 0);
    }
    *reinterpret_cast<f32x4*>(&part[((w*3+0)*64 + lane) * 4]) = acc0;
    *reinterpret_cast<f32x4*>(&part[((w*3+1)*64 + lane) * 4]) = acc1;
    *reinterpret_cast<f32x4*>(&part[((w*3+2)*64 + lane) * 4]) = acc2;
    __syncthreads();
    // gate phase: thread (b,j); D map col=lane&15, row=(lane>>4)*4+reg
    int pl = ((b >> 2) * 16 + j) * 4 + (b & 3);
    float ghr = 0.f, ghz = 0.f, ghn = 0.f;
    #pragma unroll
    for (int ww = 0; ww < 4; ++ww){
      ghr += part[(ww*3+0) * 256 + pl];
      ghz += part[(ww*3+1) * 256 + pl];
      ghn += part[(ww*3+2) * 256 + pl];
    }
    // fast gates: rcp(1+exp) sigmoid, tanh = 1 - 2*rcp(exp(2x)+1)  (~1ulp, bf16-safe)
    float r_ = __builtin_amdgcn_rcpf(1.f + __expf(-(gxr + ghr + bsh[j])));
    float z_ = __builtin_amdgcn_rcpf(1.f + __expf(-(gxz + ghz + bsh[16 + j])));
    float nx = gxn + r_ * (ghn + bsh[32 + j]);
    float n_ = 1.f - 2.f * __builtin_amdgcn_rcpf(__expf(2.f * nx) + 1.f);
    float hn = (1.f - z_) * n_ + z_ * h_old;
    h_old = hn;                                  // f32 self-path
    u16 hb = f2bf(hn);
    __hip_atomic_store(hbuf + (size_t)(par ^ 1) * (BB*HH) + (size_t)(rb0 + b) * HH + c0 + j,
                       hb, __ATOMIC_RELAXED, __HIP_MEMORY_SCOPE_AGENT);
    // per-wave drain: this wave's 64 h stores are LLC-acked, then signal
    asm volatile("s_waitcnt vmcnt(0)" ::: "memory");
    if (lane == 0)
      __hip_atomic_store(mytag, (unsigned)(base + tl + 1), __ATOMIC_RELAXED,
                         __HIP_MEMORY_SCOPE_AGENT);
    // non-critical stores after the signal
    if (h1c) h1c[((size_t)(rb0 + b) * TC + tl) * HH + c0 + j] = hb;
    if (tl == TC - 1) hstate[(size_t)(rb0 + b) * HH + c0 + j] = hn;
    __syncthreads();   // LDS `part` reuse guard (off the signal path)
    par ^= 1;
  }
}

// ---------------------------------------------------- x_projected[:, -1, :] (f32)
__global__ __launch_bounds__(256) void xproj_kernel(const float* __restrict__ x,
    const float* __restrict__ wproj, const float* __restrict__ bproj, float* __restrict__ xp){
  __shared__ float xs[II];
  int b = blockIdx.x >> 2, n0 = (blockIdx.x & 3) << 8;
  const float* xrow = x + ((size_t)b * TT + (TT - 1)) * II;
  for (int i = threadIdx.x; i < II; i += 256) xs[i] = xrow[i];
  __syncthreads();
  int n = n0 + threadIdx.x;
  const float* wrow = wproj + (size_t)n * II;
  float s = 0.f;
  #pragma unroll 4
  for (int k = 0; k < II; k += 4){
    float4 w4 = *reinterpret_cast<const float4*>(&wrow[k]);
    s += xs[k]*w4.x + xs[k+1]*w4.y + xs[k+2]*w4.z + xs[k+3]*w4.w;
  }
  xp[(size_t)b * HH + n] = s + bproj[n];
}

// ------------------------------------- residual + BN(inference) + out GEMM (f32)
__global__ __launch_bounds__(256) void final_kernel(const float* __restrict__ xp,
    const float* __restrict__ hl, const float* __restrict__ gamma, const float* __restrict__ beta,
    const float* __restrict__ mean, const float* __restrict__ var,
    const float* __restrict__ wout, const float* __restrict__ bout, float* __restrict__ out){
  __shared__ float bn[2 * HH];
  int b0 = blockIdx.x * 2;
  for (int i = threadIdx.x; i < 2 * HH; i += 256){
    int bb = i >> 10, jj = i & (HH - 1);
    float res = xp[(size_t)(b0 + bb) * HH + jj] + hl[(size_t)(b0 + bb) * HH + jj];
    bn[i] = (res - mean[jj]) * rsqrtf(var[jj] + 1e-5f) * gamma[jj] + beta[jj];
  }
  __syncthreads();
  int bb = threadIdx.x >> 7, o = threadIdx.x & (OO - 1);
  const float* wrow = wout + (size_t)o * HH;
  const float* bnrow = bn + bb * HH;
  float s = 0.f;
  #pragma unroll 4
  for (int k = 0; k < HH; k += 4){
    float4 w4 = *reinterpret_cast<const float4*>(&wrow[k]);
    s += bnrow[k]*w4.x + bnrow[k+1]*w4.y + bnrow[k+2]*w4.z + bnrow[k+3]*w4.w;
  }
  out[(size_t)(b0 + bb) * OO + o] = s + bout[o];
}

extern "C" void kernel_launch(void* const* d_in, const int* in_sizes, int n_in,
                              void* d_out, int out_size, void* d_ws, size_t ws_size,
                              hipStream_t stream) {
  const float* x      = (const float*)d_in[0];
  const float* w_proj = (const float*)d_in[1];
  const float* b_proj = (const float*)d_in[2];
  const float* w_ih0  = (const float*)d_in[3];
  const float* w_hh0  = (const float*)d_in[4];
  const float* b_ih0  = (const float*)d_in[5];
  const float* b_hh0  = (const float*)d_in[6];
  const float* w_ih1  = (const float*)d_in[7];
  const float* w_hh1  = (const float*)d_in[8];
  const float* b_ih1  = (const float*)d_in[9];
  const float* b_hh1  = (const float*)d_in[10];
  const float* gamma  = (const float*)d_in[11];
  const float* beta   = (const float*)d_in[12];
  const float* mean   = (const float*)d_in[13];
  const float* var    = (const float*)d_in[14];
  const float* w_out  = (const float*)d_in[15];
  const float* b_out  = (const float*)d_in[16];
  float* out = (float*)d_out;

  char* ws = (char*)d_ws;
  size_t off = 0;
  unsigned* tags0 = (unsigned*)(ws + off); off += (size_t)4*64*4*16*4;     // 64 KB
  unsigned* tags1 = (unsigned*)(ws + off); off += (size_t)4*64*4*16*4;     // 64 KB
  u16* hbuf0   = (u16*)(ws + off);   off += (size_t)2*BB*HH*2;             // 256 KB
  u16* hbuf1   = (u16*)(ws + off);   off += (size_t)2*BB*HH*2;
  float* hst0  = (float*)(ws + off); off += (size_t)BB*HH*4;               // 256 KB
  float* hst1  = (float*)(ws + off); off += (size_t)BB*HH*4;
  size_t zero_bytes = off;                                                 // ~1.2 MB
  float* xproj = (float*)(ws + off); off += (size_t)BB*HH*4;
  u16* xck     = (u16*)(ws + off);   off += (size_t)BB*TC*II*2;
  u16* h1c     = (u16*)(ws + off);   off += (size_t)BB*TC*HH*2;
  u16* wih0b   = (u16*)(ws + off);   off += (size_t)3*HH*II*2;
  u16* whh0b   = (u16*)(ws + off);   off += (size_t)3*HH*HH*2;
  u16* wih1b   = (u16*)(ws + off);   off += (size_t)3*HH*HH*2;
  u16* whh1b   = (u16*)(ws + off);   off += (size_t)3*HH*HH*2;
  u16* gxc     = (u16*)(ws + off);   off += (size_t)BB*TC*3*HH*2;
  // total ~62 MB

  hipMemsetAsync(d_ws, 0, zero_bytes, stream);

  cvt_kernel<<<512, 256, 0, stream>>>(w_ih0, wih0b, (3*HH*II) / 4);
  cvt_kernel<<<512, 256, 0, stream>>>(w_hh0, whh0b, (3*HH*HH) / 4);
  cvt_kernel<<<512, 256, 0, stream>>>(w_ih1, wih1b, (3*HH*HH) / 4);
  cvt_kernel<<<512, 256, 0, stream>>>(w_hh1, whh1b, (3*HH*HH) / 4);

  xproj_kernel<<<256, 256, 0, stream>>>(x, w_proj, b_proj, xproj);

  dim3 ggrid(BB * TC / 128, GN / 128);           // (32, 24)
  for (int c = 0; c < NCH; ++c){
    cvtx_chunk<<<1024, 256, 0, stream>>>(x, xck, c * TC);
    gemm_bias<II><<<ggrid, 256, 0, stream>>>(xck, wih0b, b_ih0, gxc);
    gru_layer<<<256, 256, 0, stream>>>(gxc, whh0b, b_hh0, hbuf0, tags0, h1c, hst0, c * TC);
    gemm_bias<HH><<<ggrid, 256, 0, stream>>>(h1c, wih1b, b_ih1, gxc);
    gru_layer<<<256, 256, 0, stream>>>(gxc, whh1b, b_hh1, hbuf1, tags1, nullptr, hst1, c * TC);
  }
  final_kernel<<<BB / 2, 256, 0, stream>>>(xproj, hst1, gamma, beta, mean, var, w_out, b_out, out);
}

// Round 6
// 3674.984 us; speedup vs baseline: 1.1277x; 1.1277x over previous
//
#include <hip/hip_runtime.h>
#include <math.h>

// Problem constants
#define BB 64
#define TT 512
#define II 512
#define HH 1024
#define OO 128
#define GN (3*HH)       // 3072
#define TC 64           // time chunk
#define NCH (TT/TC)     // 8 chunks

using u16 = unsigned short;
typedef __attribute__((ext_vector_type(8))) short bf16x8;
typedef __attribute__((ext_vector_type(4))) float f32x4;
typedef __attribute__((ext_vector_type(4))) unsigned short u16x4;
typedef __attribute__((ext_vector_type(2))) unsigned long long u64x2;

__device__ __forceinline__ u16 f2bf(float f){
  unsigned u = __builtin_bit_cast(unsigned, f);
  u += 0x7fffu + ((u >> 16) & 1u);          // RNE
  return (u16)(u >> 16);
}
__device__ __forceinline__ float bf2f(u16 h){
  unsigned u = ((unsigned)h) << 16;
  return __builtin_bit_cast(float, u);
}

// ---------------------------------------------------------------- f32 -> bf16
__global__ __launch_bounds__(256) void cvt_kernel(const float* __restrict__ s,
                                                  u16* __restrict__ d, int n4){
  int stride = gridDim.x * 256;
  for (int i = blockIdx.x * 256 + threadIdx.x; i < n4; i += stride){
    float4 v = reinterpret_cast<const float4*>(s)[i];
    u16x4 o; o.x = f2bf(v.x); o.y = f2bf(v.y); o.z = f2bf(v.z); o.w = f2bf(v.w);
    reinterpret_cast<u16x4*>(d)[i] = o;
  }
}

// --------------------------------------------- x chunk gather+convert to bf16
__global__ __launch_bounds__(256) void cvtx_chunk(const float* __restrict__ x,
                                                  u16* __restrict__ d, int t0){
  const int per_b = TC * II / 4;
  int stride = gridDim.x * 256;
  for (int i = blockIdx.x * 256 + threadIdx.x; i < BB * per_b; i += stride){
    int b = i / per_b, r = i - b * per_b;
    float4 v = reinterpret_cast<const float4*>(x)[(size_t)(b * TT + t0) * (II/4) + r];
    u16x4 o; o.x = f2bf(v.x); o.y = f2bf(v.y); o.z = f2bf(v.z); o.w = f2bf(v.w);
    reinterpret_cast<u16x4*>(d)[(size_t)b * per_b + r] = o;
  }
}

// ------------------------------------------------- bf16 GEMM: C = A@Bw^T + bias
// m97 structure: 128x128 tile, BK=32, 4 waves, global_load_lds width 16.
template<int K>
__global__ __launch_bounds__(256) void gemm_bias(const u16* __restrict__ A,
    const u16* __restrict__ Bw, const float* __restrict__ bias, u16* __restrict__ C){
  __shared__ u16 As[128*32];
  __shared__ u16 Bs[128*32];
  int tid = threadIdx.x;
  int lane = tid & 63, wave = tid >> 6;
  int m0 = blockIdx.x * 128, n0 = blockIdx.y * 128;
  int wr = (wave >> 1) * 64, wc = (wave & 1) * 64;
  int fr = lane & 15, fo = (lane >> 4) * 8;
  f32x4 acc[4][4] = {};
  for (int k0 = 0; k0 < K; k0 += 32){
    __syncthreads();
    #pragma unroll
    for (int c = 0; c < 2; ++c){
      int chunk = wave * 2 + c;
      int s = chunk * 64 + lane;
      int row = s >> 2, o = s & 3;
      const u16* ga = A  + (size_t)(m0 + row) * K + k0 + o * 8;
      const u16* gb = Bw + (size_t)(n0 + row) * K + k0 + o * 8;
      __builtin_amdgcn_global_load_lds(
          (const __attribute__((address_space(1))) unsigned int*)ga,
          (__attribute__((address_space(3))) unsigned int*)(As + chunk * 512), 16, 0, 0);
      __builtin_amdgcn_global_load_lds(
          (const __attribute__((address_space(1))) unsigned int*)gb,
          (__attribute__((address_space(3))) unsigned int*)(Bs + chunk * 512), 16, 0, 0);
    }
    __syncthreads();
    bf16x8 af[4], bf[4];
    #pragma unroll
    for (int m = 0; m < 4; ++m)
      af[m] = *reinterpret_cast<const bf16x8*>(&As[(wr + m*16 + fr) * 32 + fo]);
    #pragma unroll
    for (int n = 0; n < 4; ++n)
      bf[n] = *reinterpret_cast<const bf16x8*>(&Bs[(wc + n*16 + fr) * 32 + fo]);
    #pragma unroll
    for (int m = 0; m < 4; ++m)
      #pragma unroll
      for (int n = 0; n < 4; ++n)
        acc[m][n] = __builtin_amdgcn_mfma_f32_16x16x32_bf16(af[m], bf[n], acc[m][n], 0, 0, 0);
  }
  int r4 = (lane >> 4) * 4;
  #pragma unroll
  for (int n = 0; n < 4; ++n){
    int col = n0 + wc + n*16 + fr;
    float bv = bias[col];
    #pragma unroll
    for (int m = 0; m < 4; ++m){
      #pragma unroll
      for (int q = 0; q < 4; ++q){
        int row = m0 + wr + m*16 + r4 + q;
        C[(size_t)row * GN + col] = f2bf(acc[m][n][q] + bv);
      }
    }
  }
}

// --------------------------------------------------- GRU chunk body (R3 protocol)
// Per role: 128 WGs = 2 batch-groups(32 rows) x 64 col-slices(16 cols).
// W slice (48x1024 bf16, stride 1032) in LDS; h via LLC relaxed agent atomics;
// per-WG 64B-padded flags; s_sleep poll; producer signal after __syncthreads
// (vmcnt(0) drain). Proven at 228us/dispatch in R3. M=32 -> 2 MFMA A-tiles,
// 2 outputs/thread.
__device__ __forceinline__ void gru_chunk(
    const u16* __restrict__ gx, const u16* __restrict__ Whh, const float* __restrict__ bhh,
    u16* hbuf, unsigned* flags, u16* h1c, float* hstate,
    int bl, u16* Ws, float* part, float* bsh)
{
  int tid = threadIdx.x, lane = tid & 63, w = tid >> 6;
  int g = bl >> 6, wg = bl & 63;
  int c0 = wg * 16, rb0 = g * 32;
  for (int ch = tid; ch < 48 * 128; ch += 256){
    int r = ch >> 7, o = ch & 127;
    const u16* src = Whh + (size_t)((r >> 4) * HH + c0 + (r & 15)) * HH + o * 8;
    *reinterpret_cast<int4*>(&Ws[r * 1032 + o * 8]) = *reinterpret_cast<const int4*>(src);
  }
  if (tid < 48) bsh[tid] = bhh[(tid >> 4) * HH + c0 + (tid & 15)];
  __syncthreads();
  int b2 = tid >> 4, j = tid & 15;
  int fr = lane & 15, klo = (lane >> 4) * 8, kw = w * 256;
  const u16* gxp0 = gx + (size_t)(rb0 + b2) * TC * GN + c0 + j;
  const u16* gxp1 = gx + (size_t)(rb0 + 16 + b2) * TC * GN + c0 + j;
  unsigned* fgrp = flags + g * 1024;           // 64 WGs x 16 u32 (64B padded)
  float ho0 = hstate[(size_t)(rb0 + b2) * HH + c0 + j];
  float ho1 = hstate[(size_t)(rb0 + 16 + b2) * HH + c0 + j];
  int lnD = (b2 >> 2) * 16 + j, regD = b2 & 3; // D map: col=lane&15,row=(lane>>4)*4+reg
  float br = bhh[c0 + j];                       // read once (bsh also available)
  int par = 0;
  for (int tl = 0; tl < TC; ++tl){
    // gx loads are h-independent — issue before the wait, overlap the poll
    float gxr0 = bf2f(gxp0[(size_t)tl * GN]);
    float gxz0 = bf2f(gxp0[(size_t)tl * GN + HH]);
    float gxn0 = bf2f(gxp0[(size_t)tl * GN + 2 * HH]);
    float gxr1 = bf2f(gxp1[(size_t)tl * GN]);
    float gxz1 = bf2f(gxp1[(size_t)tl * GN + HH]);
    float gxn1 = bf2f(gxp1[(size_t)tl * GN + 2 * HH]);
    if (tl){
      for (;;){
        unsigned v = __hip_atomic_load(fgrp + lane * 16, __ATOMIC_RELAXED,
                                       __HIP_MEMORY_SCOPE_AGENT);
        if (__all((int)(v >= (unsigned)tl))) break;
        __builtin_amdgcn_s_sleep(1);
      }
    }
    asm volatile("" ::: "memory");   // keep h loads below the poll
    const u16* hr0 = hbuf + (size_t)par * (BB*HH) + (size_t)(rb0 + fr) * HH + kw + klo;
    const u16* hr1 = hr0 + (size_t)16 * HH;
    unsigned long long a0lo[8], a0hi[8], a1lo[8], a1hi[8];
    #pragma unroll
    for (int ks = 0; ks < 8; ++ks){
      a0lo[ks] = __hip_atomic_load((const unsigned long long*)(hr0 + ks * 32),
                                   __ATOMIC_RELAXED, __HIP_MEMORY_SCOPE_AGENT);
      a0hi[ks] = __hip_atomic_load((const unsigned long long*)(hr0 + ks * 32 + 4),
                                   __ATOMIC_RELAXED, __HIP_MEMORY_SCOPE_AGENT);
      a1lo[ks] = __hip_atomic_load((const unsigned long long*)(hr1 + ks * 32),
                                   __ATOMIC_RELAXED, __HIP_MEMORY_SCOPE_AGENT);
      a1hi[ks] = __hip_atomic_load((const unsigned long long*)(hr1 + ks * 32 + 4),
                                   __ATOMIC_RELAXED, __HIP_MEMORY_SCOPE_AGENT);
    }
    f32x4 acc[2][3] = {};
    #pragma unroll
    for (int ks = 0; ks < 8; ++ks){
      int kk = kw + ks * 32 + klo;
      bf16x8 w0 = *reinterpret_cast<const bf16x8*>(&Ws[(      fr) * 1032 + kk]);
      bf16x8 w1 = *reinterpret_cast<const bf16x8*>(&Ws[(16 + fr) * 1032 + kk]);
      bf16x8 w2 = *reinterpret_cast<const bf16x8*>(&Ws[(32 + fr) * 1032 + kk]);
      u64x2 p0; p0.x = a0lo[ks]; p0.y = a0hi[ks];
      bf16x8 af0 = __builtin_bit_cast(bf16x8, p0);
      acc[0][0] = __builtin_amdgcn_mfma_f32_16x16x32_bf16(af0, w0, acc[0][0], 0, 0, 0);
      acc[0][1] = __builtin_amdgcn_mfma_f32_16x16x32_bf16(af0, w1, acc[0][1], 0, 0, 0);
      acc[0][2] = __builtin_amdgcn_mfma_f32_16x16x32_bf16(af0, w2, acc[0][2], 0, 0, 0);
      u64x2 p1; p1.x = a1lo[ks]; p1.y = a1hi[ks];
      bf16x8 af1 = __builtin_bit_cast(bf16x8, p1);
      acc[1][0] = __builtin_amdgcn_mfma_f32_16x16x32_bf16(af1, w0, acc[1][0], 0, 0, 0);
      acc[1][1] = __builtin_amdgcn_mfma_f32_16x16x32_bf16(af1, w1, acc[1][1], 0, 0, 0);
      acc[1][2] = __builtin_amdgcn_mfma_f32_16x16x32_bf16(af1, w2, acc[1][2], 0, 0, 0);
    }
    #pragma unroll
    for (int at = 0; at < 2; ++at)
      #pragma unroll
      for (int gt = 0; gt < 3; ++gt)
        *reinterpret_cast<f32x4*>(&part[((w*6 + at*3 + gt)*64 + lane)*4]) = acc[at][gt];
    __syncthreads();
    float gh[2][3];
    #pragma unroll
    for (int at = 0; at < 2; ++at)
      #pragma unroll
      for (int gt = 0; gt < 3; ++gt){
        float s = 0.f;
        #pragma unroll
        for (int ww = 0; ww < 4; ++ww)
          s += part[((ww*6 + at*3 + gt)*64 + lnD)*4 + regD];
        gh[at][gt] = s;
      }
    float bz = bsh[16 + j], bn2 = bsh[32 + j];
    float r0 = __builtin_amdgcn_rcpf(1.f + __expf(-(gxr0 + gh[0][0] + br)));
    float z0 = __builtin_amdgcn_rcpf(1.f + __expf(-(gxz0 + gh[0][1] + bz)));
    float nx0 = gxn0 + r0 * (gh[0][2] + bn2);
    float n0 = 1.f - 2.f * __builtin_amdgcn_rcpf(__expf(2.f * nx0) + 1.f);
    float hn0 = (1.f - z0) * n0 + z0 * ho0;
    float r1 = __builtin_amdgcn_rcpf(1.f + __expf(-(gxr1 + gh[1][0] + br)));
    float z1 = __builtin_amdgcn_rcpf(1.f + __expf(-(gxz1 + gh[1][1] + bz)));
    float nx1 = gxn1 + r1 * (gh[1][2] + bn2);
    float n1 = 1.f - 2.f * __builtin_amdgcn_rcpf(__expf(2.f * nx1) + 1.f);
    float hn1 = (1.f - z1) * n1 + z1 * ho1;
    ho0 = hn0; ho1 = hn1;                        // f32 self-path
    u16 hb0 = f2bf(hn0), hb1 = f2bf(hn1);
    size_t d0 = (size_t)(par ^ 1) * (BB*HH) + (size_t)(rb0 + b2) * HH + c0 + j;
    __hip_atomic_store(hbuf + d0,               hb0, __ATOMIC_RELAXED, __HIP_MEMORY_SCOPE_AGENT);
    __hip_atomic_store(hbuf + d0 + (size_t)16*HH, hb1, __ATOMIC_RELAXED, __HIP_MEMORY_SCOPE_AGENT);
    if (h1c){
      h1c[((size_t)(rb0 + b2) * TC + tl) * HH + c0 + j] = hb0;
      h1c[((size_t)(rb0 + 16 + b2) * TC + tl) * HH + c0 + j] = hb1;
    }
    if (tl == TC - 1){
      hstate[(size_t)(rb0 + b2) * HH + c0 + j] = hn0;
      hstate[(size_t)(rb0 + 16 + b2) * HH + c0 + j] = hn1;
    }
    __syncthreads();   // vmcnt(0) drain of all WG h-stores before signaling
    if (tid == 0)
      __hip_atomic_store(fgrp + wg * 16, (unsigned)(tl + 1), __ATOMIC_RELAXED,
                         __HIP_MEMORY_SCOPE_AGENT);
    par ^= 1;
  }
}

// --------- fused dispatch: 128 WGs role A (L0 chunk c+1) || 128 WGs role B (L1 chunk c)
// No intra-kernel cross-role dataflow; each role = verbatim R3 protocol.
__global__ __launch_bounds__(256, 1) void gru_fused(
    const u16* gxA, const u16* WhhA, const float* bhhA, u16* hbufA,
    unsigned* flA, u16* h1cA, float* hstA,
    const u16* gxB, const u16* WhhB, const float* bhhB, u16* hbufB,
    unsigned* flB, float* hstB)
{
  __shared__ u16 Ws[48 * 1032];      // 99KB
  __shared__ float part[4*6*64*4];   // 24KB
  __shared__ float bsh[48];
  int blk = blockIdx.x;
  if (blk < 128){
    if (!gxA) return;
    gru_chunk(gxA, WhhA, bhhA, hbufA, flA, h1cA, hstA, blk, Ws, part, bsh);
  } else {
    if (!gxB) return;
    gru_chunk(gxB, WhhB, bhhB, hbufB, flB, nullptr, hstB, blk - 128, Ws, part, bsh);
  }
}

// ---------------------------------------------------- x_projected[:, -1, :] (f32)
__global__ __launch_bounds__(256) void xproj_kernel(const float* __restrict__ x,
    const float* __restrict__ wproj, const float* __restrict__ bproj, float* __restrict__ xp){
  __shared__ float xs[II];
  int b = blockIdx.x >> 2, n0 = (blockIdx.x & 3) << 8;
  const float* xrow = x + ((size_t)b * TT + (TT - 1)) * II;
  for (int i = threadIdx.x; i < II; i += 256) xs[i] = xrow[i];
  __syncthreads();
  int n = n0 + threadIdx.x;
  const float* wrow = wproj + (size_t)n * II;
  float s = 0.f;
  #pragma unroll 4
  for (int k = 0; k < II; k += 4){
    float4 w4 = *reinterpret_cast<const float4*>(&wrow[k]);
    s += xs[k]*w4.x + xs[k+1]*w4.y + xs[k+2]*w4.z + xs[k+3]*w4.w;
  }
  xp[(size_t)b * HH + n] = s + bproj[n];
}

// ------------------------------------- residual + BN(inference) + out GEMM (f32)
__global__ __launch_bounds__(256) void final_kernel(const float* __restrict__ xp,
    const float* __restrict__ hl, const float* __restrict__ gamma, const float* __restrict__ beta,
    const float* __restrict__ mean, const float* __restrict__ var,
    const float* __restrict__ wout, const float* __restrict__ bout, float* __restrict__ out){
  __shared__ float bn[2 * HH];
  int b0 = blockIdx.x * 2;
  for (int i = threadIdx.x; i < 2 * HH; i += 256){
    int bb = i >> 10, jj = i & (HH - 1);
    float res = xp[(size_t)(b0 + bb) * HH + jj] + hl[(size_t)(b0 + bb) * HH + jj];
    bn[i] = (res - mean[jj]) * rsqrtf(var[jj] + 1e-5f) * gamma[jj] + beta[jj];
  }
  __syncthreads();
  int bb = threadIdx.x >> 7, o = threadIdx.x & (OO - 1);
  const float* wrow = wout + (size_t)o * HH;
  const float* bnrow = bn + bb * HH;
  float s = 0.f;
  #pragma unroll 4
  for (int k = 0; k < HH; k += 4){
    float4 w4 = *reinterpret_cast<const float4*>(&wrow[k]);
    s += bnrow[k]*w4.x + bnrow[k+1]*w4.y + bnrow[k+2]*w4.z + bnrow[k+3]*w4.w;
  }
  out[(size_t)(b0 + bb) * OO + o] = s + bout[o];
}

extern "C" void kernel_launch(void* const* d_in, const int* in_sizes, int n_in,
                              void* d_out, int out_size, void* d_ws, size_t ws_size,
                              hipStream_t stream) {
  const float* x      = (const float*)d_in[0];
  const float* w_proj = (const float*)d_in[1];
  const float* b_proj = (const float*)d_in[2];
  const float* w_ih0  = (const float*)d_in[3];
  const float* w_hh0  = (const float*)d_in[4];
  const float* b_ih0  = (const float*)d_in[5];
  const float* b_hh0  = (const float*)d_in[6];
  const float* w_ih1  = (const float*)d_in[7];
  const float* w_hh1  = (const float*)d_in[8];
  const float* b_ih1  = (const float*)d_in[9];
  const float* b_hh1  = (const float*)d_in[10];
  const float* gamma  = (const float*)d_in[11];
  const float* beta   = (const float*)d_in[12];
  const float* mean   = (const float*)d_in[13];
  const float* var    = (const float*)d_in[14];
  const float* w_out  = (const float*)d_in[15];
  const float* b_out  = (const float*)d_in[16];
  float* out = (float*)d_out;

  char* ws = (char*)d_ws;
  size_t off = 0;
  // 9 fused launches x 2 roles x (2 groups x 64 WGs x 16 u32) = 18 x 8KB
  unsigned* flags = (unsigned*)(ws + off); off += (size_t)18 * 2048 * 4;   // 144 KB
  u16* hbuf0   = (u16*)(ws + off);   off += (size_t)2*BB*HH*2;             // 256 KB
  u16* hbuf1   = (u16*)(ws + off);   off += (size_t)2*BB*HH*2;
  float* hst0  = (float*)(ws + off); off += (size_t)BB*HH*4;               // 256 KB
  float* hst1  = (float*)(ws + off); off += (size_t)BB*HH*4;
  size_t zero_bytes = off;                                                 // ~1.15 MB
  float* xproj = (float*)(ws + off); off += (size_t)BB*HH*4;
  u16* xck     = (u16*)(ws + off);   off += (size_t)BB*TC*II*2;            // 4.2 MB
  u16* h1c     = (u16*)(ws + off);   off += (size_t)BB*TC*HH*2;            // 8.4 MB
  u16* wih0b   = (u16*)(ws + off);   off += (size_t)3*HH*II*2;             // 3.1 MB
  u16* whh0b   = (u16*)(ws + off);   off += (size_t)3*HH*HH*2;             // 6.3 MB
  u16* wih1b   = (u16*)(ws + off);   off += (size_t)3*HH*HH*2;
  u16* whh1b   = (u16*)(ws + off);   off += (size_t)3*HH*HH*2;
  u16* gxc0    = (u16*)(ws + off);   off += (size_t)BB*TC*3*HH*2;          // 25.2 MB
  u16* gxc1    = (u16*)(ws + off);   off += (size_t)BB*TC*3*HH*2;          // 25.2 MB
  // total ~87 MB

  hipMemsetAsync(d_ws, 0, zero_bytes, stream);

  cvt_kernel<<<512, 256, 0, stream>>>(w_ih0, wih0b, (3*HH*II) / 4);
  cvt_kernel<<<512, 256, 0, stream>>>(w_hh0, whh0b, (3*HH*HH) / 4);
  cvt_kernel<<<512, 256, 0, stream>>>(w_ih1, wih1b, (3*HH*HH) / 4);
  cvt_kernel<<<512, 256, 0, stream>>>(w_hh1, whh1b, (3*HH*HH) / 4);

  xproj_kernel<<<256, 256, 0, stream>>>(x, w_proj, b_proj, xproj);

  dim3 ggrid(BB * TC / 128, GN / 128);           // (32, 24)
  auto fl = [&](int k, int role){ return flags + (size_t)(k*2 + role) * 2048; };

  // prologue: L0 chunk 0 alone
  cvtx_chunk<<<1024, 256, 0, stream>>>(x, xck, 0);
  gemm_bias<II><<<ggrid, 256, 0, stream>>>(xck, wih0b, b_ih0, gxc0);
  gru_fused<<<256, 256, 0, stream>>>(gxc0, whh0b, b_hh0, hbuf0, fl(0,0), h1c, hst0,
                                     nullptr, whh1b, b_hh1, hbuf1, fl(0,1), hst1);
  // steady state: L1(k-1) || L0(k)
  for (int k = 1; k < NCH; ++k){
    gemm_bias<HH><<<ggrid, 256, 0, stream>>>(h1c, wih1b, b_ih1, gxc1);   // gx1(k-1)
    cvtx_chunk<<<1024, 256, 0, stream>>>(x, xck, k * TC);
    gemm_bias<II><<<ggrid, 256, 0, stream>>>(xck, wih0b, b_ih0, gxc0);   // gx0(k)
    gru_fused<<<256, 256, 0, stream>>>(gxc0, whh0b, b_hh0, hbuf0, fl(k,0), h1c, hst0,
                                       gxc1, whh1b, b_hh1, hbuf1, fl(k,1), hst1);
  }
  // epilogue: L1 chunk 7 alone
  gemm_bias<HH><<<ggrid, 256, 0, stream>>>(h1c, wih1b, b_ih1, gxc1);
  gru_fused<<<256, 256, 0, stream>>>(nullptr, whh0b, b_hh0, hbuf0, fl(8,0), h1c, hst0,
                                     gxc1, whh1b, b_hh1, hbuf1, fl(8,1), hst1);

  final_kernel<<<BB / 2, 256, 0, stream>>>(xproj, hst1, gamma, beta, mean, var, w_out, b_out, out);
}

// Round 7
// 3069.793 us; speedup vs baseline: 1.3501x; 1.1971x over previous
//
#include <hip/hip_runtime.h>
#include <math.h>

// Problem constants
#define BB 64
#define TT 512
#define II 512
#define HH 1024
#define OO 128
#define GN (3*HH)       // 3072
#define TC 64           // time chunk
#define NCH (TT/TC)     // 8 chunks
#define NSLOT 66        // rolling h slots: slot 0 = initial zeros, 1..65 rotate

using u16 = unsigned short;
typedef __attribute__((ext_vector_type(8))) short bf16x8;
typedef __attribute__((ext_vector_type(4))) float f32x4;
typedef __attribute__((ext_vector_type(4))) unsigned short u16x4;

__device__ __forceinline__ u16 f2bf(float f){
  unsigned u = __builtin_bit_cast(unsigned, f);
  u += 0x7fffu + ((u >> 16) & 1u);          // RNE
  return (u16)(u >> 16);
}
__device__ __forceinline__ float bf2f(u16 h){
  unsigned u = ((unsigned)h) << 16;
  return __builtin_bit_cast(float, u);
}

// ---------------------------------------------------------------- f32 -> bf16
__global__ __launch_bounds__(256) void cvt_kernel(const float* __restrict__ s,
                                                  u16* __restrict__ d, int n4){
  int stride = gridDim.x * 256;
  for (int i = blockIdx.x * 256 + threadIdx.x; i < n4; i += stride){
    float4 v = reinterpret_cast<const float4*>(s)[i];
    u16x4 o; o.x = f2bf(v.x); o.y = f2bf(v.y); o.z = f2bf(v.z); o.w = f2bf(v.w);
    reinterpret_cast<u16x4*>(d)[i] = o;
  }
}

// --------------------------------------------- x chunk gather+convert to bf16
__global__ __launch_bounds__(256) void cvtx_chunk(const float* __restrict__ x,
                                                  u16* __restrict__ d, int t0){
  const int per_b = TC * II / 4;
  int stride = gridDim.x * 256;
  for (int i = blockIdx.x * 256 + threadIdx.x; i < BB * per_b; i += stride){
    int b = i / per_b, r = i - b * per_b;
    float4 v = reinterpret_cast<const float4*>(x)[(size_t)(b * TT + t0) * (II/4) + r];
    u16x4 o; o.x = f2bf(v.x); o.y = f2bf(v.y); o.z = f2bf(v.z); o.w = f2bf(v.w);
    reinterpret_cast<u16x4*>(d)[(size_t)b * per_b + r] = o;
  }
}

// ------------------------------------------------- bf16 GEMM: C = A@Bw^T + bias
// m97 structure: 128x128 tile, BK=32, 4 waves, global_load_lds width 16.
template<int K>
__global__ __launch_bounds__(256) void gemm_bias(const u16* __restrict__ A,
    const u16* __restrict__ Bw, const float* __restrict__ bias, u16* __restrict__ C){
  __shared__ u16 As[128*32];
  __shared__ u16 Bs[128*32];
  int tid = threadIdx.x;
  int lane = tid & 63, wave = tid >> 6;
  int m0 = blockIdx.x * 128, n0 = blockIdx.y * 128;
  int wr = (wave >> 1) * 64, wc = (wave & 1) * 64;
  int fr = lane & 15, fo = (lane >> 4) * 8;
  f32x4 acc[4][4] = {};
  for (int k0 = 0; k0 < K; k0 += 32){
    __syncthreads();
    #pragma unroll
    for (int c = 0; c < 2; ++c){
      int chunk = wave * 2 + c;
      int s = chunk * 64 + lane;
      int row = s >> 2, o = s & 3;
      const u16* ga = A  + (size_t)(m0 + row) * K + k0 + o * 8;
      const u16* gb = Bw + (size_t)(n0 + row) * K + k0 + o * 8;
      __builtin_amdgcn_global_load_lds(
          (const __attribute__((address_space(1))) unsigned int*)ga,
          (__attribute__((address_space(3))) unsigned int*)(As + chunk * 512), 16, 0, 0);
      __builtin_amdgcn_global_load_lds(
          (const __attribute__((address_space(1))) unsigned int*)gb,
          (__attribute__((address_space(3))) unsigned int*)(Bs + chunk * 512), 16, 0, 0);
    }
    __syncthreads();
    bf16x8 af[4], bf[4];
    #pragma unroll
    for (int m = 0; m < 4; ++m)
      af[m] = *reinterpret_cast<const bf16x8*>(&As[(wr + m*16 + fr) * 32 + fo]);
    #pragma unroll
    for (int n = 0; n < 4; ++n)
      bf[n] = *reinterpret_cast<const bf16x8*>(&Bs[(wc + n*16 + fr) * 32 + fo]);
    #pragma unroll
    for (int m = 0; m < 4; ++m)
      #pragma unroll
      for (int n = 0; n < 4; ++n)
        acc[m][n] = __builtin_amdgcn_mfma_f32_16x16x32_bf16(af[m], bf[n], acc[m][n], 0, 0, 0);
  }
  int r4 = (lane >> 4) * 4;
  #pragma unroll
  for (int n = 0; n < 4; ++n){
    int col = n0 + wc + n*16 + fr;
    float bv = bias[col];
    #pragma unroll
    for (int m = 0; m < 4; ++m){
      #pragma unroll
      for (int q = 0; q < 4; ++q){
        int row = m0 + wr + m*16 + r4 + q;
        C[(size_t)row * GN + col] = f2bf(acc[m][n][q] + bv);
      }
    }
  }
}

// --------------------------------------------------- GRU chunk body
// Per role: 128 WGs = 2 batch-groups(32 rows) x 64 col-slices(16 cols).
// W slice (48x1024 bf16, stride 1032) in LDS.
// R7 h-exchange: rolling 66-slot hbuf indexed by GLOBAL step t.
//   write slot = (t % 65)+1, read slot = ((t-1) % 65)+1, slot 0 = zeros (t=0).
//   Producers: relaxed agent atomic 2B stores (write-through to LLC) +
//   __syncthreads (vmcnt drain) + per-WG flag (R3-proven protocol).
//   Consumers: flags poll, then PLAIN CACHED 16B loads — every read address is
//   first-touch within the dispatch (mod-65 window) and dispatch-boundary
//   acquire invalidates XCD L2s, so no stale line can exist; first reader per
//   XCD misses to LLC, the rest hit local L2. Kills the R6 bottleneck
//   (16 MB/step of 8B uncached atomic loads saturating ~2.5 TB/s).
//   Producer lead bounded to 1 step by the flag wait << 65 slots.
__device__ __forceinline__ void gru_chunk(
    const u16* __restrict__ gx, const u16* __restrict__ Whh, const float* __restrict__ bhh,
    u16* hbuf, unsigned* flags, u16* h1c, float* hstate, int base,
    int bl, u16* Ws, float* part, float* bsh)
{
  int tid = threadIdx.x, lane = tid & 63, w = tid >> 6;
  int g = bl >> 6, wg = bl & 63;
  int c0 = wg * 16, rb0 = g * 32;
  for (int ch = tid; ch < 48 * 128; ch += 256){
    int r = ch >> 7, o = ch & 127;
    const u16* src = Whh + (size_t)((r >> 4) * HH + c0 + (r & 15)) * HH + o * 8;
    *reinterpret_cast<int4*>(&Ws[r * 1032 + o * 8]) = *reinterpret_cast<const int4*>(src);
  }
  if (tid < 48) bsh[tid] = bhh[(tid >> 4) * HH + c0 + (tid & 15)];
  __syncthreads();
  int b2 = tid >> 4, j = tid & 15;
  int fr = lane & 15, klo = (lane >> 4) * 8, kw = w * 256;
  const u16* gxp0 = gx + (size_t)(rb0 + b2) * TC * GN + c0 + j;
  const u16* gxp1 = gx + (size_t)(rb0 + 16 + b2) * TC * GN + c0 + j;
  unsigned* fgrp = flags + g * 1024;           // 64 WGs x 16 u32 (64B padded)
  float ho0 = hstate[(size_t)(rb0 + b2) * HH + c0 + j];
  float ho1 = hstate[(size_t)(rb0 + 16 + b2) * HH + c0 + j];
  int lnD = (b2 >> 2) * 16 + j, regD = b2 & 3; // D map: col=lane&15,row=(lane>>4)*4+reg
  float br = bhh[c0 + j];
  for (int tl = 0; tl < TC; ++tl){
    int t = base + tl;
    // gx loads are h-independent — issue before the wait, overlap the poll
    float gxr0 = bf2f(gxp0[(size_t)tl * GN]);
    float gxz0 = bf2f(gxp0[(size_t)tl * GN + HH]);
    float gxn0 = bf2f(gxp0[(size_t)tl * GN + 2 * HH]);
    float gxr1 = bf2f(gxp1[(size_t)tl * GN]);
    float gxz1 = bf2f(gxp1[(size_t)tl * GN + HH]);
    float gxn1 = bf2f(gxp1[(size_t)tl * GN + 2 * HH]);
    if (tl){
      for (;;){
        unsigned v = __hip_atomic_load(fgrp + lane * 16, __ATOMIC_RELAXED,
                                       __HIP_MEMORY_SCOPE_AGENT);
        if (__all((int)(v >= (unsigned)tl))) break;
        __builtin_amdgcn_s_sleep(1);
      }
    }
    asm volatile("" ::: "memory");   // keep h loads below the poll
    // ---- h loads: PLAIN CACHED 16B loads from the read slot (first-touch)
    const u16* rslot = hbuf + (size_t)(((t - 1) % 65) + 1) * (BB * HH);
    const u16* hr0 = rslot + (size_t)(rb0 + fr) * HH + kw + klo;
    const u16* hr1 = hr0 + (size_t)16 * HH;
    bf16x8 af0[8], af1[8];
    #pragma unroll
    for (int ks = 0; ks < 8; ++ks){
      af0[ks] = *reinterpret_cast<const bf16x8*>(hr0 + ks * 32);
      af1[ks] = *reinterpret_cast<const bf16x8*>(hr1 + ks * 32);
    }
    f32x4 acc[2][3] = {};
    #pragma unroll
    for (int ks = 0; ks < 8; ++ks){
      int kk = kw + ks * 32 + klo;
      bf16x8 w0 = *reinterpret_cast<const bf16x8*>(&Ws[(      fr) * 1032 + kk]);
      bf16x8 w1 = *reinterpret_cast<const bf16x8*>(&Ws[(16 + fr) * 1032 + kk]);
      bf16x8 w2 = *reinterpret_cast<const bf16x8*>(&Ws[(32 + fr) * 1032 + kk]);
      acc[0][0] = __builtin_amdgcn_mfma_f32_16x16x32_bf16(af0[ks], w0, acc[0][0], 0, 0, 0);
      acc[0][1] = __builtin_amdgcn_mfma_f32_16x16x32_bf16(af0[ks], w1, acc[0][1], 0, 0, 0);
      acc[0][2] = __builtin_amdgcn_mfma_f32_16x16x32_bf16(af0[ks], w2, acc[0][2], 0, 0, 0);
      acc[1][0] = __builtin_amdgcn_mfma_f32_16x16x32_bf16(af1[ks], w0, acc[1][0], 0, 0, 0);
      acc[1][1] = __builtin_amdgcn_mfma_f32_16x16x32_bf16(af1[ks], w1, acc[1][1], 0, 0, 0);
      acc[1][2] = __builtin_amdgcn_mfma_f32_16x16x32_bf16(af1[ks], w2, acc[1][2], 0, 0, 0);
    }
    #pragma unroll
    for (int at = 0; at < 2; ++at)
      #pragma unroll
      for (int gt = 0; gt < 3; ++gt)
        *reinterpret_cast<f32x4*>(&part[((w*6 + at*3 + gt)*64 + lane)*4]) = acc[at][gt];
    __syncthreads();
    float gh[2][3];
    #pragma unroll
    for (int at = 0; at < 2; ++at)
      #pragma unroll
      for (int gt = 0; gt < 3; ++gt){
        float s = 0.f;
        #pragma unroll
        for (int ww = 0; ww < 4; ++ww)
          s += part[((ww*6 + at*3 + gt)*64 + lnD)*4 + regD];
        gh[at][gt] = s;
      }
    float bz = bsh[16 + j], bn2 = bsh[32 + j];
    float r0 = __builtin_amdgcn_rcpf(1.f + __expf(-(gxr0 + gh[0][0] + br)));
    float z0 = __builtin_amdgcn_rcpf(1.f + __expf(-(gxz0 + gh[0][1] + bz)));
    float nx0 = gxn0 + r0 * (gh[0][2] + bn2);
    float n0 = 1.f - 2.f * __builtin_amdgcn_rcpf(__expf(2.f * nx0) + 1.f);
    float hn0 = (1.f - z0) * n0 + z0 * ho0;
    float r1 = __builtin_amdgcn_rcpf(1.f + __expf(-(gxr1 + gh[1][0] + br)));
    float z1 = __builtin_amdgcn_rcpf(1.f + __expf(-(gxz1 + gh[1][1] + bz)));
    float nx1 = gxn1 + r1 * (gh[1][2] + bn2);
    float n1 = 1.f - 2.f * __builtin_amdgcn_rcpf(__expf(2.f * nx1) + 1.f);
    float hn1 = (1.f - z1) * n1 + z1 * ho1;
    ho0 = hn0; ho1 = hn1;                        // f32 self-path
    u16 hb0 = f2bf(hn0), hb1 = f2bf(hn1);
    // ---- h stores: device-scope write-through to LLC at the write slot
    u16* wslot = hbuf + (size_t)((t % 65) + 1) * (BB * HH);
    size_t d0 = (size_t)(rb0 + b2) * HH + c0 + j;
    __hip_atomic_store(wslot + d0,                hb0, __ATOMIC_RELAXED, __HIP_MEMORY_SCOPE_AGENT);
    __hip_atomic_store(wslot + d0 + (size_t)16*HH, hb1, __ATOMIC_RELAXED, __HIP_MEMORY_SCOPE_AGENT);
    if (h1c){
      h1c[((size_t)(rb0 + b2) * TC + tl) * HH + c0 + j] = hb0;
      h1c[((size_t)(rb0 + 16 + b2) * TC + tl) * HH + c0 + j] = hb1;
    }
    if (tl == TC - 1){
      hstate[(size_t)(rb0 + b2) * HH + c0 + j] = hn0;
      hstate[(size_t)(rb0 + 16 + b2) * HH + c0 + j] = hn1;
    }
    __syncthreads();   // vmcnt(0) drain of all WG h-stores before signaling
    if (tid == 0)
      __hip_atomic_store(fgrp + wg * 16, (unsigned)(tl + 1), __ATOMIC_RELAXED,
                         __HIP_MEMORY_SCOPE_AGENT);
  }
}

// --------- fused dispatch: 128 WGs role A (L0 chunk c) || 128 WGs role B (L1 chunk c-1)
__global__ __launch_bounds__(256, 1) void gru_fused(
    const u16* gxA, const u16* WhhA, const float* bhhA, u16* hbufA,
    unsigned* flA, u16* h1cA, float* hstA, int baseA,
    const u16* gxB, const u16* WhhB, const float* bhhB, u16* hbufB,
    unsigned* flB, float* hstB, int baseB)
{
  __shared__ u16 Ws[48 * 1032];      // 99KB
  __shared__ float part[4*6*64*4];   // 24KB
  __shared__ float bsh[48];
  int blk = blockIdx.x;
  if (blk < 128){
    if (!gxA) return;
    gru_chunk(gxA, WhhA, bhhA, hbufA, flA, h1cA, hstA, baseA, blk, Ws, part, bsh);
  } else {
    if (!gxB) return;
    gru_chunk(gxB, WhhB, bhhB, hbufB, flB, nullptr, hstB, baseB, blk - 128, Ws, part, bsh);
  }
}

// ---------------------------------------------------- x_projected[:, -1, :] (f32)
__global__ __launch_bounds__(256) void xproj_kernel(const float* __restrict__ x,
    const float* __restrict__ wproj, const float* __restrict__ bproj, float* __restrict__ xp){
  __shared__ float xs[II];
  int b = blockIdx.x >> 2, n0 = (blockIdx.x & 3) << 8;
  const float* xrow = x + ((size_t)b * TT + (TT - 1)) * II;
  for (int i = threadIdx.x; i < II; i += 256) xs[i] = xrow[i];
  __syncthreads();
  int n = n0 + threadIdx.x;
  const float* wrow = wproj + (size_t)n * II;
  float s = 0.f;
  #pragma unroll 4
  for (int k = 0; k < II; k += 4){
    float4 w4 = *reinterpret_cast<const float4*>(&wrow[k]);
    s += xs[k]*w4.x + xs[k+1]*w4.y + xs[k+2]*w4.z + xs[k+3]*w4.w;
  }
  xp[(size_t)b * HH + n] = s + bproj[n];
}

// ------------------------------------- residual + BN(inference) + out GEMM (f32)
__global__ __launch_bounds__(256) void final_kernel(const float* __restrict__ xp,
    const float* __restrict__ hl, const float* __restrict__ gamma, const float* __restrict__ beta,
    const float* __restrict__ mean, const float* __restrict__ var,
    const float* __restrict__ wout, const float* __restrict__ bout, float* __restrict__ out){
  __shared__ float bn[2 * HH];
  int b0 = blockIdx.x * 2;
  for (int i = threadIdx.x; i < 2 * HH; i += 256){
    int bb = i >> 10, jj = i & (HH - 1);
    float res = xp[(size_t)(b0 + bb) * HH + jj] + hl[(size_t)(b0 + bb) * HH + jj];
    bn[i] = (res - mean[jj]) * rsqrtf(var[jj] + 1e-5f) * gamma[jj] + beta[jj];
  }
  __syncthreads();
  int bb = threadIdx.x >> 7, o = threadIdx.x & (OO - 1);
  const float* wrow = wout + (size_t)o * HH;
  const float* bnrow = bn + bb * HH;
  float s = 0.f;
  #pragma unroll 4
  for (int k = 0; k < HH; k += 4){
    float4 w4 = *reinterpret_cast<const float4*>(&wrow[k]);
    s += bnrow[k]*w4.x + bnrow[k+1]*w4.y + bnrow[k+2]*w4.z + bnrow[k+3]*w4.w;
  }
  out[(size_t)(b0 + bb) * OO + o] = s + bout[o];
}

extern "C" void kernel_launch(void* const* d_in, const int* in_sizes, int n_in,
                              void* d_out, int out_size, void* d_ws, size_t ws_size,
                              hipStream_t stream) {
  const float* x      = (const float*)d_in[0];
  const float* w_proj = (const float*)d_in[1];
  const float* b_proj = (const float*)d_in[2];
  const float* w_ih0  = (const float*)d_in[3];
  const float* w_hh0  = (const float*)d_in[4];
  const float* b_ih0  = (const float*)d_in[5];
  const float* b_hh0  = (const float*)d_in[6];
  const float* w_ih1  = (const float*)d_in[7];
  const float* w_hh1  = (const float*)d_in[8];
  const float* b_ih1  = (const float*)d_in[9];
  const float* b_hh1  = (const float*)d_in[10];
  const float* gamma  = (const float*)d_in[11];
  const float* beta   = (const float*)d_in[12];
  const float* mean   = (const float*)d_in[13];
  const float* var    = (const float*)d_in[14];
  const float* w_out  = (const float*)d_in[15];
  const float* b_out  = (const float*)d_in[16];
  float* out = (float*)d_out;

  char* ws = (char*)d_ws;
  size_t off = 0;
  unsigned* flags = (unsigned*)(ws + off); off += (size_t)18 * 2048 * 4;   // 144 KB
  float* hst0  = (float*)(ws + off); off += (size_t)BB*HH*4;               // 256 KB
  float* hst1  = (float*)(ws + off); off += (size_t)BB*HH*4;
  size_t zeroA = off;                                                      // flags+hstates
  u16* hbuf0   = (u16*)(ws + off);   off += (size_t)NSLOT*BB*HH*2;         // 8.65 MB
  u16* hbuf1   = (u16*)(ws + off);   off += (size_t)NSLOT*BB*HH*2;
  float* xproj = (float*)(ws + off); off += (size_t)BB*HH*4;
  u16* xck     = (u16*)(ws + off);   off += (size_t)BB*TC*II*2;            // 4.2 MB
  u16* h1c     = (u16*)(ws + off);   off += (size_t)BB*TC*HH*2;            // 8.4 MB
  u16* wih0b   = (u16*)(ws + off);   off += (size_t)3*HH*II*2;             // 3.1 MB
  u16* whh0b   = (u16*)(ws + off);   off += (size_t)3*HH*HH*2;             // 6.3 MB
  u16* wih1b   = (u16*)(ws + off);   off += (size_t)3*HH*HH*2;
  u16* whh1b   = (u16*)(ws + off);   off += (size_t)3*HH*HH*2;
  u16* gxc0    = (u16*)(ws + off);   off += (size_t)BB*TC*3*HH*2;          // 25.2 MB
  u16* gxc1    = (u16*)(ws + off);   off += (size_t)BB*TC*3*HH*2;
  // total ~104 MB

  hipMemsetAsync(d_ws, 0, zeroA, stream);                    // flags + hstates
  hipMemsetAsync(hbuf0, 0, (size_t)BB*HH*2, stream);         // slot 0 = h(-1) = 0
  hipMemsetAsync(hbuf1, 0, (size_t)BB*HH*2, stream);

  cvt_kernel<<<512, 256, 0, stream>>>(w_ih0, wih0b, (3*HH*II) / 4);
  cvt_kernel<<<512, 256, 0, stream>>>(w_hh0, whh0b, (3*HH*HH) / 4);
  cvt_kernel<<<512, 256, 0, stream>>>(w_ih1, wih1b, (3*HH*HH) / 4);
  cvt_kernel<<<512, 256, 0, stream>>>(w_hh1, whh1b, (3*HH*HH) / 4);

  xproj_kernel<<<256, 256, 0, stream>>>(x, w_proj, b_proj, xproj);

  dim3 ggrid(BB * TC / 128, GN / 128);           // (32, 24)
  auto fl = [&](int k, int role){ return flags + (size_t)(k*2 + role) * 2048; };

  // prologue: L0 chunk 0 alone
  cvtx_chunk<<<1024, 256, 0, stream>>>(x, xck, 0);
  gemm_bias<II><<<ggrid, 256, 0, stream>>>(xck, wih0b, b_ih0, gxc0);
  gru_fused<<<256, 256, 0, stream>>>(gxc0, whh0b, b_hh0, hbuf0, fl(0,0), h1c, hst0, 0,
                                     nullptr, whh1b, b_hh1, hbuf1, fl(0,1), hst1, 0);
  // steady state: L0(k) || L1(k-1)
  for (int k = 1; k < NCH; ++k){
    gemm_bias<HH><<<ggrid, 256, 0, stream>>>(h1c, wih1b, b_ih1, gxc1);   // gx1(k-1)
    cvtx_chunk<<<1024, 256, 0, stream>>>(x, xck, k * TC);
    gemm_bias<II><<<ggrid, 256, 0, stream>>>(xck, wih0b, b_ih0, gxc0);   // gx0(k)
    gru_fused<<<256, 256, 0, stream>>>(gxc0, whh0b, b_hh0, hbuf0, fl(k,0), h1c, hst0, k*TC,
                                       gxc1, whh1b, b_hh1, hbuf1, fl(k,1), hst1, (k-1)*TC);
  }
  // epilogue: L1 chunk 7 alone
  gemm_bias<HH><<<ggrid, 256, 0, stream>>>(h1c, wih1b, b_ih1, gxc1);
  gru_fused<<<256, 256, 0, stream>>>(nullptr, whh0b, b_hh0, hbuf0, fl(8,0), h1c, hst0, 0,
                                     gxc1, whh1b, b_hh1, hbuf1, fl(8,1), hst1, (NCH-1)*TC);

  final_kernel<<<BB / 2, 256, 0, stream>>>(xproj, hst1, gamma, beta, mean, var, w_out, b_out, out);
}